// Round 8
// baseline (246.154 us; speedup 1.0000x reference)
//
#include <hip/hip_runtime.h>
#include <hip/hip_cooperative_groups.h>
#include <math.h>

namespace cg = cooperative_groups;

#define NB 10
#define HH 100
#define TABN 2048
#define TAB_MAX 11.2f
#define INV_DELTA ((float)TABN / TAB_MAX)

// ---------------------------------------------------------------------------
// Sizes: B=8, N=64, C=64, H=100, R=10
// ws layout (floats):
//   tab     [2049][100]          = 204900   @ 0
//   M       [512 zb][6400 ho]    = 3276800  @ 204900
//   partial [8 z][64 b][64][64]  = 2097152  @ 3481700
//   s2      [8 z][16 ac][64]     = 8192     @ 5578852
// ONE cooperative kernel: 512 blocks x 256 threads, 51.7 KB LDS
// -> 2-3 blocks/CU resident (R4's failure was 1 block/CU at 103 KB).
// Phases: A(table+M) -> B(Y) -> C(red) -> D(final), grid.sync between.
// ---------------------------------------------------------------------------

__global__ __launch_bounds__(256) void fused_kernel(
    const float* __restrict__ in1, const float* __restrict__ in2,
    const float* __restrict__ xyz1, const float* __restrict__ xyz2,
    const int* __restrict__ mask,
    const float* __restrict__ w1, const float* __restrict__ w2,
    const float* __restrict__ w3,
    const float* __restrict__ fc3w, const float* __restrict__ fc2w,
    float* __restrict__ tab, float* __restrict__ Mg,
    float* __restrict__ partial, float* __restrict__ s2,
    float* __restrict__ out)
{
    __shared__ union {
        struct { float sw1[NB * HH]; float basis[8][NB]; float h1[8][HH]; } pt;
        struct { float x[16][64]; } pm;
        struct { float M[6400]; float h2T[6400]; int i0[64]; float f[64]; } pb;
        struct { float red[4][64]; float sn[64]; } pcd;
    } sm;

    cg::grid_group grid = cg::this_grid();
    const int bid = blockIdx.x, tid = threadIdx.x;

    // ================= Phase A: table (bid<257) | M (257<=bid<481) =========
    if (bid < 257) {
        for (int i = tid; i < NB * HH; i += 256) sm.pt.sw1[i] = w1[i];

        int p0 = bid * 8;
        const float DELTA = TAB_MAX / (float)TABN;
        const float STEP = 10.0f / 9.0f;
        const float HALF_PI = 1.57079632679489662f;

        if (tid < 8 * NB) {
            int p = tid / NB, j = tid % NB;
            float r = (float)(p0 + p) * DELTA;
            float u = (r - (float)j * STEP) * (HALF_PI / STEP);
            float c = __cosf(u);
            sm.pt.basis[p][j] = (fabsf(u) < HALF_PI) ? c * c : 0.0f;
        }
        __syncthreads();

        const float inv_sqrt10 = 0.31622776601683794f;
        for (int task = tid; task < 8 * HH; task += 256) {
            int p = task / HH, k = task % HH;
            float acc = 0.f;
            #pragma unroll
            for (int j = 0; j < NB; ++j) acc += sm.pt.basis[p][j] * sm.pt.sw1[j * HH + k];
            acc *= inv_sqrt10;
            float sg = 1.0f / (1.0f + __expf(-acc));
            sm.pt.h1[p][k] = acc * sg;
        }
        __syncthreads();

        if (tid < 8 * 25) {
            int p = tid / 25, k2g = tid % 25;
            int idx = p0 + p;
            float4 acc = make_float4(0.f, 0.f, 0.f, 0.f);
            #pragma unroll 4
            for (int k = 0; k < HH; ++k) {
                float hv = sm.pt.h1[p][k];
                float4 wv = *(const float4*)(w2 + (size_t)k * HH + k2g * 4);
                acc.x += hv * wv.x; acc.y += hv * wv.y; acc.z += hv * wv.z; acc.w += hv * wv.w;
            }
            if (idx <= TABN) {
                float4 o; float a;
                a = acc.x * 0.1f; o.x = a / (1.0f + __expf(-a));
                a = acc.y * 0.1f; o.y = a / (1.0f + __expf(-a));
                a = acc.z * 0.1f; o.z = a / (1.0f + __expf(-a));
                a = acc.w * 0.1f; o.w = a / (1.0f + __expf(-a));
                *(float4*)(tab + (size_t)idx * HH + k2g * 4) = o;
            }
        }
    } else if (bid < 481) {
        // M[zb][h*64+o] = sum_i w3[h][o*64+i] * x[zb][i]  (LDS-staged x)
        int m = bid - 257;                 // 0..223
        int zbg = m / 7, yc = m % 7;       // 32 zb-groups of 16, 7 task-chunks

        {
            int lz = tid >> 4, q = tid & 15;
            int zb = zbg * 16 + lz;
            int z = zb >> 6, b = zb & 63;
            const float* src = (b < 32) ? (in1 + (size_t)(z * 32 + b) * 64)
                                        : (in2 + (size_t)(z * 32 + (b - 32)) * 64);
            *(float4*)&sm.pm.x[lz][q * 4] = *(const float4*)(src + q * 4);
        }
        __syncthreads();

        int task = yc * 256 + tid;         // (h, og): 1600 tasks
        if (task < 1600) {
            int h = task >> 4, og = task & 15;
            const float* wbase = w3 + (size_t)h * 4096 + og * 256;

            float4 acc[16];
            #pragma unroll
            for (int l = 0; l < 16; ++l) acc[l] = make_float4(0.f, 0.f, 0.f, 0.f);

            const float4* sx4 = (const float4*)sm.pm.x;
            #pragma unroll 2
            for (int i4 = 0; i4 < 16; ++i4) {
                float4 wa = *(const float4*)(wbase + i4 * 4);
                float4 wb = *(const float4*)(wbase + 64 + i4 * 4);
                float4 wc = *(const float4*)(wbase + 128 + i4 * 4);
                float4 wd = *(const float4*)(wbase + 192 + i4 * 4);
                #pragma unroll
                for (int l = 0; l < 16; ++l) {
                    float4 xv = sx4[l * 16 + i4];
                    acc[l].x += wa.x * xv.x + wa.y * xv.y + wa.z * xv.z + wa.w * xv.w;
                    acc[l].y += wb.x * xv.x + wb.y * xv.y + wb.z * xv.z + wb.w * xv.w;
                    acc[l].z += wc.x * xv.x + wc.y * xv.y + wc.z * xv.z + wc.w * xv.w;
                    acc[l].w += wd.x * xv.x + wd.y * xv.y + wd.z * xv.z + wd.w * xv.w;
                }
            }
            #pragma unroll
            for (int l = 0; l < 16; ++l) {
                int zb = zbg * 16 + l;
                *(float4*)(Mg + (size_t)zb * 6400 + h * 64 + og * 4) = acc[l];
            }
        }
    }

    grid.sync();

    // ================= Phase B: Y partial, one (z,b) per block =============
    {
        const int z = bid >> 6, b = bid & 63;

        if (tid < 64) {
            int a = tid;
            const float* pa = (a < 32) ? (xyz1 + (size_t)(z * 32 + a) * 3)
                                       : (xyz2 + (size_t)(z * 32 + (a - 32)) * 3);
            const float* pb = (b < 32) ? (xyz1 + (size_t)(z * 32 + b) * 3)
                                       : (xyz2 + (size_t)(z * 32 + (b - 32)) * 3);
            float dx = pa[0] - pb[0], dy = pa[1] - pb[1], dz = pa[2] - pb[2];
            float r = sqrtf(dx * dx + dy * dy + dz * dz + 1e-12f);
            float t = r * INV_DELTA;
            int i0 = (int)t;
            i0 = (i0 < TABN - 1) ? i0 : (TABN - 1);
            float f = t - (float)i0;
            sm.pb.i0[a] = i0;
            sm.pb.f[a] = (f < 1.0f) ? f : 1.0f;
        }
        {
            const float4* Msrc = (const float4*)(Mg + (size_t)(z * 64 + b) * 6400);
            float4* sM4 = (float4*)sm.pb.M;
            for (int i = tid; i < 1600; i += 256) sM4[i] = Msrc[i];
        }
        __syncthreads();

        for (int task = tid; task < 1600; task += 256) {
            int a4 = task / 100, c = task - a4 * 100;
            float4 hv;
            #pragma unroll
            for (int k = 0; k < 4; ++k) {
                int a = a4 * 4 + k;
                int i0 = sm.pb.i0[a];
                float f = sm.pb.f[a];
                const float* tp = tab + (size_t)i0 * HH + c;
                float v0 = tp[0], v1 = tp[HH];
                ((float*)&hv)[k] = fmaf(f, v1 - v0, v0);
            }
            *(float4*)&sm.pb.h2T[c * 64 + ((a4 ^ (c & 7)) << 2)] = hv;
        }
        __syncthreads();

        const int og = tid & 15, ag = tid >> 4;
        float4 acc0 = make_float4(0.f, 0.f, 0.f, 0.f);
        float4 acc1 = make_float4(0.f, 0.f, 0.f, 0.f);
        float4 acc2 = make_float4(0.f, 0.f, 0.f, 0.f);
        float4 acc3 = make_float4(0.f, 0.f, 0.f, 0.f);

        #pragma unroll 4
        for (int c = 0; c < 100; ++c) {
            float4 mv = *(const float4*)&sm.pb.M[c * 64 + og * 4];
            float4 hv = *(const float4*)&sm.pb.h2T[c * 64 + ((ag ^ (c & 7)) << 2)];
            acc0.x += hv.x * mv.x; acc0.y += hv.x * mv.y; acc0.z += hv.x * mv.z; acc0.w += hv.x * mv.w;
            acc1.x += hv.y * mv.x; acc1.y += hv.y * mv.y; acc1.z += hv.y * mv.z; acc1.w += hv.y * mv.w;
            acc2.x += hv.z * mv.x; acc2.y += hv.z * mv.y; acc2.z += hv.z * mv.z; acc2.w += hv.z * mv.w;
            acc3.x += hv.w * mv.x; acc3.y += hv.w * mv.y; acc3.z += hv.w * mv.z; acc3.w += hv.w * mv.w;
        }

        size_t base = ((size_t)(z * 64 + b) * 64 + ag * 4) * 64 + og * 4;
        *(float4*)&partial[base]       = acc0;
        *(float4*)&partial[base + 64]  = acc1;
        *(float4*)&partial[base + 128] = acc2;
        *(float4*)&partial[base + 192] = acc3;
    }

    grid.sync();

    // ================= Phase C: reduce over b, abs+mask+scale ==============
    if (bid < 128) {
        int z = bid >> 4, ac = bid & 15;
        int o = tid & 63, ar = tid >> 6;
        int a = ac * 4 + ar;

        float val = 0.f;
        #pragma unroll 8
        for (int b = 0; b < 64; ++b)
            val += partial[((size_t)(z * 64 + b) * 64 + a) * 64 + o];

        const float scale = 0.0125f;   // (1/sqrt(100)) * (1/sqrt(64))
        float m = (mask[z * 64 + a] != 0) ? scale : 0.0f;
        sm.pcd.red[ar][o] = fabsf(val) * m;
        __syncthreads();
        if (tid < 64)
            s2[((size_t)z * 16 + ac) * 64 + o] =
                sm.pcd.red[0][o] + sm.pcd.red[1][o] + sm.pcd.red[2][o] + sm.pcd.red[3][o];
    }

    grid.sync();

    // ================= Phase D: normalize + fc3 + fc2 + sigmoid ============
    if (bid < 8) {
        int z = bid;
        if (tid < 64) {
            float s = 0.f;
            #pragma unroll
            for (int ac = 0; ac < 16; ++ac) s += s2[((size_t)z * 16 + ac) * 64 + tid];
            float tot = s;
            #pragma unroll
            for (int d = 32; d >= 1; d >>= 1) tot += __shfl_xor(tot, d, 64);
            float mean = tot * (1.0f / 64.0f);
            float dv = s - mean;
            float v2 = dv * dv;
            #pragma unroll
            for (int d = 32; d >= 1; d >>= 1) v2 += __shfl_xor(v2, d, 64);
            float var = v2 * (1.0f / 63.0f);   // ddof=1
            sm.pcd.sn[tid] = dv / (sqrtf(var) + 1e-6f);
        }
        __syncthreads();
        if (tid < 64) {
            float acc = 0.f;
            #pragma unroll 8
            for (int i = 0; i < 64; ++i) acc += sm.pcd.sn[i] * fc3w[i * 64 + tid];
            acc *= 0.125f;
            float t = (acc > 0.f) ? acc : 0.01f * acc;
            float pr = t * fc2w[tid];
            #pragma unroll
            for (int d = 32; d >= 1; d >>= 1) pr += __shfl_xor(pr, d, 64);
            if (tid == 0) out[z] = 1.0f / (1.0f + expf(-0.125f * pr));
        }
    }
}

extern "C" void kernel_launch(void* const* d_in, const int* in_sizes, int n_in,
                              void* d_out, int out_size, void* d_ws, size_t ws_size,
                              hipStream_t stream) {
    const float* in1  = (const float*)d_in[0];
    const float* in2  = (const float*)d_in[1];
    const float* xyz1 = (const float*)d_in[2];
    const float* xyz2 = (const float*)d_in[3];
    const int*   mask = (const int*)d_in[4];
    const float* w1   = (const float*)d_in[5];
    const float* w2   = (const float*)d_in[6];
    const float* w3   = (const float*)d_in[7];
    const float* fc3w = (const float*)d_in[8];
    const float* fc2w = (const float*)d_in[9];
    float* out = (float*)d_out;

    float* ws      = (float*)d_ws;
    float* tab     = ws;                  // 204900
    float* Mg      = ws + 204900;         // 3276800
    float* partial = ws + 3481700;        // 2097152
    float* s2      = ws + 5578852;        // 8192

    void* args[] = { (void*)&in1, (void*)&in2, (void*)&xyz1, (void*)&xyz2,
                     (void*)&mask, (void*)&w1, (void*)&w2, (void*)&w3,
                     (void*)&fc3w, (void*)&fc2w,
                     (void*)&tab, (void*)&Mg, (void*)&partial, (void*)&s2,
                     (void*)&out };
    hipLaunchCooperativeKernel((void*)fused_kernel, dim3(512), dim3(256),
                               args, 0, stream);
}

// Round 9
// 62.515 us; speedup vs baseline: 3.9375x; 3.9375x over previous
//
#include <hip/hip_runtime.h>
#include <math.h>

#define NB 10
#define HH 100
#define TABN 2048
#define TAB_MAX 11.2f
#define INV_DELTA ((float)TABN / TAB_MAX)

// ---------------------------------------------------------------------------
// Sizes: B=8, N=64, C=64, H=100, R=10
// ws layout (floats):
//   tab     [2049][100]          = 204900   @ 0
//   M       [512 zb][6400 ho]    = 3276800  @ 204900
//   partial [8 z][64 b][64][64]  = 2097152  @ 3481700
// 3 kernels (tm, Y, rf), 2 boundaries. All wide, no fences, no atomics.
// ---------------------------------------------------------------------------

// Fused: blocks 0..256 build the h2 lookup table; blocks 257..480 build M.
__global__ __launch_bounds__(256) void tm_kernel(
    const float* __restrict__ in1, const float* __restrict__ in2,
    const float* __restrict__ w1, const float* __restrict__ w2,
    const float* __restrict__ w3,
    float* __restrict__ tab, float* __restrict__ Mout)
{
    __shared__ float s_w1[NB * HH];
    __shared__ float s_basis[8][NB];
    __shared__ float s_h1[8][HH];
    __shared__ float s_x[16][64];

    int tid = threadIdx.x;

    if (blockIdx.x < 257) {
        // ------------------- table path -------------------
        for (int i = tid; i < NB * HH; i += 256) s_w1[i] = w1[i];

        int p0 = blockIdx.x * 8;
        const float DELTA = TAB_MAX / (float)TABN;
        const float STEP = 10.0f / 9.0f;
        const float HALF_PI = 1.57079632679489662f;

        if (tid < 8 * NB) {
            int p = tid / NB, j = tid % NB;
            float r = (float)(p0 + p) * DELTA;
            float u = (r - (float)j * STEP) * (HALF_PI / STEP);
            float c = __cosf(u);
            s_basis[p][j] = (fabsf(u) < HALF_PI) ? c * c : 0.0f;
        }
        __syncthreads();

        const float inv_sqrt10 = 0.31622776601683794f;
        for (int task = tid; task < 8 * HH; task += 256) {
            int p = task / HH, k = task % HH;
            float acc = 0.f;
            #pragma unroll
            for (int j = 0; j < NB; ++j) acc += s_basis[p][j] * s_w1[j * HH + k];
            acc *= inv_sqrt10;
            float sg = 1.0f / (1.0f + __expf(-acc));
            s_h1[p][k] = acc * sg;
        }
        __syncthreads();

        if (tid < 8 * 25) {
            int p = tid / 25, k2g = tid % 25;
            int idx = p0 + p;
            float4 acc = make_float4(0.f, 0.f, 0.f, 0.f);
            #pragma unroll 4
            for (int k = 0; k < HH; ++k) {
                float hv = s_h1[p][k];
                float4 wv = *(const float4*)(w2 + (size_t)k * HH + k2g * 4);
                acc.x += hv * wv.x; acc.y += hv * wv.y; acc.z += hv * wv.z; acc.w += hv * wv.w;
            }
            if (idx <= TABN) {
                float4 o; float a;
                a = acc.x * 0.1f; o.x = a / (1.0f + __expf(-a));
                a = acc.y * 0.1f; o.y = a / (1.0f + __expf(-a));
                a = acc.z * 0.1f; o.z = a / (1.0f + __expf(-a));
                a = acc.w * 0.1f; o.w = a / (1.0f + __expf(-a));
                *(float4*)(tab + (size_t)idx * HH + k2g * 4) = o;
            }
        }
    } else {
        // ------------------- M path (LDS-staged x) -------------------
        // M[zb][h*64+o] = sum_i w3[h][o*64+i] * x[zb][i]
        int m = blockIdx.x - 257;          // 0..223
        int zbg = m / 7, yc = m % 7;       // 32 zb-groups of 16, 7 task-chunks

        {
            int lz = tid >> 4, q = tid & 15;
            int zb = zbg * 16 + lz;
            int z = zb >> 6, b = zb & 63;
            const float* src = (b < 32) ? (in1 + (size_t)(z * 32 + b) * 64)
                                        : (in2 + (size_t)(z * 32 + (b - 32)) * 64);
            *(float4*)&s_x[lz][q * 4] = *(const float4*)(src + q * 4);
        }
        __syncthreads();

        int task = yc * 256 + tid;         // (h, og): 1600 tasks
        if (task < 1600) {
            int h = task >> 4, og = task & 15;
            const float* wbase = w3 + (size_t)h * 4096 + og * 256;

            float4 acc[16];
            #pragma unroll
            for (int l = 0; l < 16; ++l) acc[l] = make_float4(0.f, 0.f, 0.f, 0.f);

            const float4* sx4 = (const float4*)s_x;
            #pragma unroll 2
            for (int i4 = 0; i4 < 16; ++i4) {
                float4 wa = *(const float4*)(wbase + i4 * 4);
                float4 wb = *(const float4*)(wbase + 64 + i4 * 4);
                float4 wc = *(const float4*)(wbase + 128 + i4 * 4);
                float4 wd = *(const float4*)(wbase + 192 + i4 * 4);
                #pragma unroll
                for (int l = 0; l < 16; ++l) {
                    float4 xv = sx4[l * 16 + i4];
                    acc[l].x += wa.x * xv.x + wa.y * xv.y + wa.z * xv.z + wa.w * xv.w;
                    acc[l].y += wb.x * xv.x + wb.y * xv.y + wb.z * xv.z + wb.w * xv.w;
                    acc[l].z += wc.x * xv.x + wc.y * xv.y + wc.z * xv.z + wc.w * xv.w;
                    acc[l].w += wd.x * xv.x + wd.y * xv.y + wd.z * xv.z + wd.w * xv.w;
                }
            }
            #pragma unroll
            for (int l = 0; l < 16; ++l) {
                int zb = zbg * 16 + l;
                *(float4*)(Mout + (size_t)zb * 6400 + h * 64 + og * 4) = acc[l];
            }
        }
    }
}

// Y partial per (z,b): 256 threads, out tile 64a x 64o, thread = 4a x 4o.
// 2 ds_read_b128 per 16 FMA; 51.7 KB LDS -> 3 blocks/CU, 12 waves/CU.
__global__ __launch_bounds__(256) void kernel_Y(
    const float* __restrict__ xyz1, const float* __restrict__ xyz2,
    const float* __restrict__ tab, const float* __restrict__ M,
    float* __restrict__ partial)
{
    __shared__ float s_M[6400];     // 25.6 KB
    __shared__ float s_h2T[6400];   // 25.6 KB, [c][a] swizzled
    __shared__ int   s_i0[64];
    __shared__ float s_f[64];

    const int z = blockIdx.x, b = blockIdx.y;
    const int tid = threadIdx.x;   // 0..255

    if (tid < 64) {
        int a = tid;
        const float* pa = (a < 32) ? (xyz1 + (size_t)(z * 32 + a) * 3)
                                   : (xyz2 + (size_t)(z * 32 + (a - 32)) * 3);
        const float* pb = (b < 32) ? (xyz1 + (size_t)(z * 32 + b) * 3)
                                   : (xyz2 + (size_t)(z * 32 + (b - 32)) * 3);
        float dx = pa[0] - pb[0], dy = pa[1] - pb[1], dz = pa[2] - pb[2];
        float r = sqrtf(dx * dx + dy * dy + dz * dz + 1e-12f);
        float t = r * INV_DELTA;
        int i0 = (int)t;
        i0 = (i0 < TABN - 1) ? i0 : (TABN - 1);
        float f = t - (float)i0;
        s_i0[a] = i0;
        s_f[a] = (f < 1.0f) ? f : 1.0f;
    }
    // stage M[h][o] for this (z,b)
    {
        const float4* Msrc = (const float4*)(M + (size_t)(z * 64 + b) * 6400);
        float4* sM4 = (float4*)s_M;
        for (int i = tid; i < 1600; i += 256) sM4[i] = Msrc[i];
    }
    __syncthreads();

    // lerp h2 transposed+swizzled: task = (a4, c)
    for (int task = tid; task < 1600; task += 256) {
        int a4 = task / 100, c = task - a4 * 100;
        float4 hv;
        #pragma unroll
        for (int k = 0; k < 4; ++k) {
            int a = a4 * 4 + k;
            int i0 = s_i0[a];
            float f = s_f[a];
            const float* tp = tab + (size_t)i0 * HH + c;
            float v0 = tp[0], v1 = tp[HH];
            ((float*)&hv)[k] = fmaf(f, v1 - v0, v0);
        }
        *(float4*)&s_h2T[c * 64 + ((a4 ^ (c & 7)) << 2)] = hv;
    }
    __syncthreads();

    const int og = tid & 15, ag = tid >> 4;
    float4 acc0 = make_float4(0.f, 0.f, 0.f, 0.f);
    float4 acc1 = make_float4(0.f, 0.f, 0.f, 0.f);
    float4 acc2 = make_float4(0.f, 0.f, 0.f, 0.f);
    float4 acc3 = make_float4(0.f, 0.f, 0.f, 0.f);

    #pragma unroll 4
    for (int c = 0; c < 100; ++c) {
        float4 mv = *(const float4*)&s_M[c * 64 + og * 4];
        float4 hv = *(const float4*)&s_h2T[c * 64 + ((ag ^ (c & 7)) << 2)];
        acc0.x += hv.x * mv.x; acc0.y += hv.x * mv.y; acc0.z += hv.x * mv.z; acc0.w += hv.x * mv.w;
        acc1.x += hv.y * mv.x; acc1.y += hv.y * mv.y; acc1.z += hv.y * mv.z; acc1.w += hv.y * mv.w;
        acc2.x += hv.z * mv.x; acc2.y += hv.z * mv.y; acc2.z += hv.z * mv.z; acc2.w += hv.z * mv.w;
        acc3.x += hv.w * mv.x; acc3.y += hv.w * mv.y; acc3.z += hv.w * mv.z; acc3.w += hv.w * mv.w;
    }

    size_t base = ((size_t)(z * 64 + b) * 64 + ag * 4) * 64 + og * 4;
    *(float4*)&partial[base]       = acc0;
    *(float4*)&partial[base + 64]  = acc1;
    *(float4*)&partial[base + 128] = acc2;
    *(float4*)&partial[base + 192] = acc3;
}

// rf: one block per z, 1024 threads (16 waves). Wave w handles a-quad w:
// sum partial over b (fixed order), abs+mask+scale, LDS-reduce over quads,
// then wave 0: layernorm (ddof=1) + fc3+leaky + fc2 + sigmoid.
// Plain loads/stores only — the kernel boundary provides coherence.
__global__ __launch_bounds__(1024) void kernel_rf(
    const float* __restrict__ partial, const int* __restrict__ mask,
    const float* __restrict__ fc3w, const float* __restrict__ fc2w,
    float* __restrict__ out)
{
    __shared__ float sred[16][64];
    __shared__ float s_sn[64];

    const int z = blockIdx.x;
    const int tid = threadIdx.x;
    const int o = tid & 63;
    const int aq = tid >> 6;      // 0..15, wave index == a-quad

    float s0 = 0.f, s1 = 0.f, s2v = 0.f, s3 = 0.f;
    const float* pz = partial + (size_t)z * 262144 + (size_t)aq * 256 + o;
    #pragma unroll 4
    for (int b = 0; b < 64; ++b) {
        const float* p = pz + (size_t)b * 4096;
        s0 += p[0];
        s1 += p[64];
        s2v += p[128];
        s3 += p[192];
    }

    const float scale = 0.0125f;   // (1/sqrt(100)) * (1/sqrt(64))
    const int* mz = mask + z * 64 + aq * 4;
    float local = 0.f;
    local += (mz[0] != 0) ? fabsf(s0) * scale : 0.f;
    local += (mz[1] != 0) ? fabsf(s1) * scale : 0.f;
    local += (mz[2] != 0) ? fabsf(s2v) * scale : 0.f;
    local += (mz[3] != 0) ? fabsf(s3) * scale : 0.f;
    sred[aq][o] = local;
    __syncthreads();

    if (tid < 64) {
        float s = 0.f;
        #pragma unroll
        for (int g = 0; g < 16; ++g) s += sred[g][o];

        float tot = s;
        #pragma unroll
        for (int d = 32; d >= 1; d >>= 1) tot += __shfl_xor(tot, d, 64);
        float mean = tot * (1.0f / 64.0f);
        float dv = s - mean;
        float v2 = dv * dv;
        #pragma unroll
        for (int d = 32; d >= 1; d >>= 1) v2 += __shfl_xor(v2, d, 64);
        float var = v2 * (1.0f / 63.0f);   // ddof=1
        s_sn[o] = dv / (sqrtf(var) + 1e-6f);
    }
    __syncthreads();

    if (tid < 64) {
        float accf = 0.f;
        #pragma unroll 8
        for (int i = 0; i < 64; ++i) accf += s_sn[i] * fc3w[i * 64 + o];
        accf *= 0.125f;                    // 1/sqrt(C)
        float t = (accf > 0.f) ? accf : 0.01f * accf;
        float pr = t * fc2w[o];
        #pragma unroll
        for (int d = 32; d >= 1; d >>= 1) pr += __shfl_xor(pr, d, 64);
        if (o == 0 && tid < 64) out[z] = 1.0f / (1.0f + expf(-0.125f * pr));
    }
}

extern "C" void kernel_launch(void* const* d_in, const int* in_sizes, int n_in,
                              void* d_out, int out_size, void* d_ws, size_t ws_size,
                              hipStream_t stream) {
    const float* in1  = (const float*)d_in[0];
    const float* in2  = (const float*)d_in[1];
    const float* xyz1 = (const float*)d_in[2];
    const float* xyz2 = (const float*)d_in[3];
    const int*   mask = (const int*)d_in[4];
    const float* w1   = (const float*)d_in[5];
    const float* w2   = (const float*)d_in[6];
    const float* w3   = (const float*)d_in[7];
    const float* fc3w = (const float*)d_in[8];
    const float* fc2w = (const float*)d_in[9];
    float* out = (float*)d_out;

    float* ws      = (float*)d_ws;
    float* tab     = ws;                           // 204900
    float* Mg      = ws + 204900;                  // 3276800
    float* partial = ws + 3481700;                 // 2097152

    tm_kernel<<<481, 256, 0, stream>>>(in1, in2, w1, w2, w3, tab, Mg);
    kernel_Y<<<dim3(8, 64), 256, 0, stream>>>(xyz1, xyz2, tab, Mg, partial);
    kernel_rf<<<8, 1024, 0, stream>>>(partial, mask, fc3w, fc2w, out);
}